// Round 3
// baseline (153.000 us; speedup 1.0000x reference)
//
#include <hip/hip_runtime.h>

// Problem constants (static per reference setup_inputs)
#define BB     16
#define HH     128
#define WW     8192
#define N_MAXC 128
#define W_OUTC 6271
#define SEP_CLASS 2.0f

// d_out layout (all float32): x_new [B*H*W_OUT] | xi_new [B*N_MAX*2] | xl_new [B*W_OUT]
#define X_ELEMS (BB * HH * W_OUTC)
#define XI_OFF  (X_ELEMS)
#define XL_OFF  (X_ELEMS + BB * N_MAXC * 2)

#define MAP_BYTES ((size_t)(BB * W_OUTC) * sizeof(int))

#define TCOLS  1024   // gather map tile (columns)
#define HROWS  16     // gather rows per block
#define MTILE  896    // meta columns per block (7 * 896 = 6272 >= 6271)

// ---------------- kernel A: map + xi_new + xl_new (parallel scan) ----------------
__global__ __launch_bounds__(256) void tb_meta(const int* __restrict__ xi,
                                               const int* __restrict__ Nv,
                                               const int* __restrict__ xl,
                                               float* __restrict__ out,
                                               int* __restrict__ map) {
    __shared__ int s_s0[N_MAXC], s_e0[N_MAXC], s_scan[N_MAXC], s_sn[N_MAXC], s_en[N_MAXC];
    const int b   = blockIdx.x;
    const int tid = threadIdx.x;
    const int Nb  = Nv[b];

    int wv = 0;
    if (tid < N_MAXC) {
        int2 se = ((const int2*)xi)[b * N_MAXC + tid];
        s_s0[tid] = se.x; s_e0[tid] = se.y;
        int w = se.y - se.x; if (w < 0) w = 0;
        wv = (tid < Nb) ? w : 0;
        s_scan[tid] = wv;
    }
    __syncthreads();
    // Hillis-Steele inclusive scan over 128 entries (reference: cumsum of masked widths)
    #pragma unroll
    for (int off = 1; off < N_MAXC; off <<= 1) {
        int v = 0;
        if (tid < N_MAXC && tid >= off) v = s_scan[tid - off];
        __syncthreads();
        if (tid < N_MAXC) s_scan[tid] += v;
        __syncthreads();
    }
    if (tid < N_MAXC) {
        int c = s_scan[tid];
        s_sn[tid] = c - wv + tid;   // sn = csum - w_valid + i
        s_en[tid] = c + tid;        // en = csum + i
    }
    __syncthreads();

    if (blockIdx.y == 0 && tid < N_MAXC) {
        const bool valid = tid < Nb;
        out[XI_OFF + (b * N_MAXC + tid) * 2 + 0] = valid ? (float)s_sn[tid] : 0.0f;
        out[XI_OFF + (b * N_MAXC + tid) * 2 + 1] = valid ? (float)s_en[tid] : 0.0f;
    }

    const int t_lo = blockIdx.y * MTILE;
    const int t_hi = (t_lo + MTILE < W_OUTC) ? t_lo + MTILE : W_OUTC;
    for (int t = t_lo + tid; t < t_hi; t += 256) {
        // i = #{valid j : en[j] <= t}; en strictly increasing on [0,Nb)
        int lo = 0, hi = Nb;
        while (lo < hi) { int mid = (lo + hi) >> 1; if (s_en[mid] <= t) lo = mid + 1; else hi = mid; }
        const int i  = lo;
        const int ic = (i < N_MAXC - 1) ? i : (N_MAXC - 1);
        int m = -2;
        if (i < Nb) {
            int sn = s_sn[ic], en = s_en[ic];
            if (t >= sn && en > sn && s_e0[ic] > s_s0[ic]) {
                int src = s_s0[ic] + (t - sn);
                src = src < 0 ? 0 : (src > WW - 1 ? WW - 1 : src);
                m = src;
            }
        }
        if (m == -2 && i >= 1) {
            int ep = s_en[i - 1];
            if (t == ep && (i - 1) < (Nb - 1) && ep < WW) m = -1;
        }
        if (map) map[b * W_OUTC + t] = m;
        float v = (m >= 0) ? (float)xl[b * WW + m] : ((m == -1) ? SEP_CLASS : 0.0f);
        out[XL_OFF + b * W_OUTC + t] = v;
    }
}

// ---------------- kernel B (primary): LDS-map gather with row ILP ----------------
// Block = 1024-col tile x 16 rows. Map tile in LDS (reused 16x); 16 independent
// x-loads in flight per thread via unroll-4 over rows x 4 col-strides.
__global__ __launch_bounds__(256) void tb_gather(const float* __restrict__ x,
                                                 const int* __restrict__ map,
                                                 const float* __restrict__ sep_param,
                                                 float* __restrict__ out) {
    __shared__ int s_map[TCOLS];
    const int t0   = blockIdx.x * TCOLS;
    const int h0   = blockIdx.y * HROWS;
    const int b    = blockIdx.z;
    const int tid  = threadIdx.x;
    const int tmax = W_OUTC - t0;       // columns in this tile
    const float sep = sep_param[0];

    for (int j = tid; j < TCOLS; j += 256) {
        int t = t0 + j;
        s_map[j] = (t < W_OUTC) ? map[b * W_OUTC + t] : -2;
    }
    __syncthreads();

    const float* xb = x   + (size_t)(b * HH + h0) * WW;
    float*       ob = out + (size_t)(b * HH + h0) * W_OUTC + t0;

    if (tmax >= TCOLS) {                // full tile: no guards
        #pragma unroll 4
        for (int r = 0; r < HROWS; ++r) {
            const float* xr   = xb + (size_t)r * WW;
            float*       orow = ob + (size_t)r * W_OUTC;
            #pragma unroll
            for (int k = 0; k < 4; ++k) {
                const int j = k * 256 + tid;
                const int m = s_map[j];
                const int a = (m >= 0) ? m : 0;
                const float xv = xr[a];                       // unconditional clamped load
                orow[j] = (m >= 0) ? xv : ((m == -1) ? sep : 0.0f);
            }
        }
    } else {                            // tail tile (127 cols)
        #pragma unroll 4
        for (int r = 0; r < HROWS; ++r) {
            const float* xr   = xb + (size_t)r * WW;
            float*       orow = ob + (size_t)r * W_OUTC;
            #pragma unroll
            for (int k = 0; k < 4; ++k) {
                const int j = k * 256 + tid;
                if (j < tmax) {
                    const int m = s_map[j];
                    const int a = (m >= 0) ? m : 0;
                    const float xv = xr[a];
                    orow[j] = (m >= 0) ? xv : ((m == -1) ? sep : 0.0f);
                }
            }
        }
    }
}

// ---------------- fallback (no ws): self-contained tiled gather ----------------
#define FTILE   512
#define FHCHUNK 32

__device__ __forceinline__ void fb_scan(const int* __restrict__ xi, int b, int Nb,
                                        int* s_s0, int* s_e0, int* s_sn, int* s_en, int tid) {
    if (tid < N_MAXC) {
        s_s0[tid] = xi[(b * N_MAXC + tid) * 2 + 0];
        s_e0[tid] = xi[(b * N_MAXC + tid) * 2 + 1];
    }
    __syncthreads();
    if (tid == 0) {
        int c = 0;
        for (int i = 0; i < N_MAXC; ++i) {
            int w = s_e0[i] - s_s0[i]; if (w < 0) w = 0;
            int wvv = (i < Nb) ? w : 0;
            c += wvv;
            s_sn[i] = c - wvv + i;
            s_en[i] = c + i;
        }
    }
    __syncthreads();
}

__global__ __launch_bounds__(256) void tb_gather_tiled(const float* __restrict__ x,
                                                       const int* __restrict__ xi,
                                                       const int* __restrict__ Nv,
                                                       const float* __restrict__ sep_param,
                                                       float* __restrict__ out) {
    __shared__ int s_s0[N_MAXC], s_e0[N_MAXC], s_sn[N_MAXC], s_en[N_MAXC];
    __shared__ int s_map[FTILE];
    const int b = blockIdx.z, h0 = blockIdx.y * FHCHUNK, t0 = blockIdx.x * FTILE;
    const int tid = threadIdx.x, Nb = Nv[b];
    fb_scan(xi, b, Nb, s_s0, s_e0, s_sn, s_en, tid);
    for (int j = tid; j < FTILE; j += 256) {
        int t = t0 + j, m = -2;
        if (t < W_OUTC) {
            int lo = 0, hi = Nb;
            while (lo < hi) { int mid = (lo + hi) >> 1; if (s_en[mid] <= t) lo = mid + 1; else hi = mid; }
            int i = lo, ic = (i < N_MAXC - 1) ? i : (N_MAXC - 1);
            if (i < Nb) {
                int sn = s_sn[ic], en = s_en[ic];
                if (t >= sn && en > sn && s_e0[ic] > s_s0[ic]) {
                    int src = s_s0[ic] + (t - sn);
                    m = src < 0 ? 0 : (src > WW - 1 ? WW - 1 : src);
                }
            }
            if (m == -2 && i >= 1) {
                int ep = s_en[i - 1];
                if (t == ep && (i - 1) < (Nb - 1) && ep < WW) m = -1;
            }
        }
        s_map[j] = m;
    }
    __syncthreads();
    const float sep = sep_param[0];
    const float* xb = x + (size_t)b * HH * WW;
    float* ob = out + (size_t)b * HH * W_OUTC;
    for (int r = 0; r < FHCHUNK; ++r) {
        const int h = h0 + r;
        const float* xr = xb + (size_t)h * WW;
        float* orow = ob + (size_t)h * W_OUTC;
        for (int j = tid; j < FTILE; j += 256) {
            int t = t0 + j;
            if (t < W_OUTC) {
                int m = s_map[j];
                orow[t] = (m >= 0) ? xr[m] : ((m == -1) ? sep : 0.0f);
            }
        }
    }
}

extern "C" void kernel_launch(void* const* d_in, const int* in_sizes, int n_in,
                              void* d_out, int out_size, void* d_ws, size_t ws_size,
                              hipStream_t stream) {
    const float* x   = (const float*)d_in[0];
    const int*   xi  = (const int*)  d_in[1];
    const int*   Nv  = (const int*)  d_in[2];
    const int*   xl  = (const int*)  d_in[3];
    const float* sep = (const float*)d_in[4];
    float*       out = (float*)d_out;

    const bool use_ws = (ws_size >= MAP_BYTES) && (d_ws != nullptr);
    int* map = use_ws ? (int*)d_ws : nullptr;

    tb_meta<<<dim3(BB, 7), dim3(256), 0, stream>>>(xi, Nv, xl, out, map);

    if (use_ws) {
        dim3 grid((W_OUTC + TCOLS - 1) / TCOLS, HH / HROWS, BB);   // 7 x 8 x 16 = 896 blocks
        tb_gather<<<grid, dim3(256), 0, stream>>>(x, map, sep, out);
    } else {
        dim3 grid((W_OUTC + FTILE - 1) / FTILE, HH / FHCHUNK, BB);
        tb_gather_tiled<<<grid, dim3(256), 0, stream>>>(x, xi, Nv, sep, out);
    }
}

// Round 4
// 135.603 us; speedup vs baseline: 1.1283x; 1.1283x over previous
//
#include <hip/hip_runtime.h>

// Problem constants (static per reference setup_inputs)
#define BB     16
#define HH     128
#define WW     8192
#define N_MAXC 128
#define W_OUTC 6271
#define SEP_CLASS 2.0f

// d_out layout (all float32): x_new [B*H*W_OUT] | xi_new [B*N_MAX*2] | xl_new [B*W_OUT]
#define X_ELEMS (BB * HH * W_OUTC)            // 12,843,008
#define XI_OFF  (X_ELEMS)
#define XL_OFF  (X_ELEMS + BB * N_MAXC * 2)   // 12,847,104
#define NCHUNKS (X_ELEMS / 4)                 // 3,210,752 float4 chunks

#define MAP_BYTES ((size_t)(BB * W_OUTC) * sizeof(int))

#define GBLK  1568                            // gather grid (blocks of 256)
#define GSTR  (GBLK * 256)                    // 401,408 threads
#define GITER 8                               // chunks per thread: 8*GSTR >= NCHUNKS

#define MTILE 512                             // meta cols per block; 13*512 >= 6271

// ---------------- kernel A: map + xi_new + xl_new ----------------
__global__ __launch_bounds__(256) void tb_meta(const int* __restrict__ xi,
                                               const int* __restrict__ Nv,
                                               const int* __restrict__ xl,
                                               float* __restrict__ out,
                                               int* __restrict__ map) {
    __shared__ int s_s0[N_MAXC], s_e0[N_MAXC], s_scan[N_MAXC], s_sn[N_MAXC], s_en[N_MAXC];
    const int b   = blockIdx.x;
    const int tid = threadIdx.x;
    const int Nb  = Nv[b];

    int wv = 0;
    if (tid < N_MAXC) {
        int2 se = ((const int2*)xi)[b * N_MAXC + tid];
        s_s0[tid] = se.x; s_e0[tid] = se.y;
        int w = se.y - se.x; if (w < 0) w = 0;
        wv = (tid < Nb) ? w : 0;
        s_scan[tid] = wv;
    }
    __syncthreads();
    // Hillis-Steele inclusive scan (reference: cumsum of masked widths)
    #pragma unroll
    for (int off = 1; off < N_MAXC; off <<= 1) {
        int v = 0;
        if (tid < N_MAXC && tid >= off) v = s_scan[tid - off];
        __syncthreads();
        if (tid < N_MAXC) s_scan[tid] += v;
        __syncthreads();
    }
    if (tid < N_MAXC) {
        int c = s_scan[tid];
        s_sn[tid] = c - wv + tid;   // sn = csum - w_valid + i
        s_en[tid] = c + tid;        // en = csum + i
    }
    __syncthreads();

    if (blockIdx.y == 0 && tid < N_MAXC) {
        const bool valid = tid < Nb;
        out[XI_OFF + (b * N_MAXC + tid) * 2 + 0] = valid ? (float)s_sn[tid] : 0.0f;
        out[XI_OFF + (b * N_MAXC + tid) * 2 + 1] = valid ? (float)s_en[tid] : 0.0f;
    }

    const int t_lo = blockIdx.y * MTILE;
    const int t_hi = (t_lo + MTILE < W_OUTC) ? t_lo + MTILE : W_OUTC;
    for (int t = t_lo + tid; t < t_hi; t += 256) {
        // i = #{valid j : en[j] <= t}; en strictly increasing on [0,Nb)
        int lo = 0, hi = Nb;
        while (lo < hi) { int mid = (lo + hi) >> 1; if (s_en[mid] <= t) lo = mid + 1; else hi = mid; }
        const int i  = lo;
        const int ic = (i < N_MAXC - 1) ? i : (N_MAXC - 1);
        int m = -2;
        if (i < Nb) {
            int sn = s_sn[ic], en = s_en[ic];
            if (t >= sn && en > sn && s_e0[ic] > s_s0[ic]) {
                int src = s_s0[ic] + (t - sn);
                src = src < 0 ? 0 : (src > WW - 1 ? WW - 1 : src);
                m = src;
            }
        }
        if (m == -2 && i >= 1) {
            int ep = s_en[i - 1];
            if (t == ep && (i - 1) < (Nb - 1) && ep < WW) m = -1;
        }
        if (map) map[b * W_OUTC + t] = m;
        float v = (m >= 0) ? (float)xl[b * WW + m] : ((m == -1) ? SEP_CLASS : 0.0f);
        out[XL_OFF + b * W_OUTC + t] = v;
    }
}

// ---------------- kernel B (primary): phase-batched flat gather ----------------
// Each thread owns 8 float4 chunks (32 elems). Three phases over local arrays
// with compile-time indices: 32 map loads | 32 x loads | 8 float4 stores.
// Only 2 latency exposures per 32 elements.
__global__ __launch_bounds__(256) void tb_gather_flat(const float* __restrict__ x,
                                                      const int* __restrict__ map,
                                                      const float* __restrict__ sep_param,
                                                      float* __restrict__ out) {
    const unsigned gtid = blockIdx.x * 256u + threadIdx.x;
    const float sep = sep_param[0];

    unsigned rowA[GITER], colA[GITER];
    int      mv[GITER][4];
    float    xv[GITER][4];

    // phase 0: addresses (VALU only; magic-div by constant 6271)
    #pragma unroll
    for (int j = 0; j < GITER; ++j) {
        unsigned c = gtid + (unsigned)j * (unsigned)GSTR;
        if (c >= (unsigned)NCHUNKS) c = NCHUNKS - 1;   // clamp; store is guarded below
        const unsigned flat = c * 4u;
        const unsigned bh   = flat / (unsigned)W_OUTC;
        rowA[j] = bh;
        colA[j] = flat - bh * (unsigned)W_OUTC;
    }
    // phase 1: 32 independent map loads (L2-resident, 401KB)
    #pragma unroll
    for (int j = 0; j < GITER; ++j) {
        #pragma unroll
        for (int k = 0; k < 4; ++k) {
            unsigned tk = colA[j] + (unsigned)k;
            unsigned r  = rowA[j];
            if (tk >= (unsigned)W_OUTC) { tk -= (unsigned)W_OUTC; r += 1u; }  // row wrap
            mv[j][k] = map[(r >> 7) * (unsigned)W_OUTC + tk];
        }
    }
    // phase 2: 32 independent clamped x loads
    #pragma unroll
    for (int j = 0; j < GITER; ++j) {
        #pragma unroll
        for (int k = 0; k < 4; ++k) {
            unsigned tk = colA[j] + (unsigned)k;
            unsigned r  = rowA[j];
            if (tk >= (unsigned)W_OUTC) r += 1u;
            const int m = mv[j][k];
            const unsigned a = (m >= 0) ? (unsigned)m : 0u;
            xv[j][k] = x[((size_t)r << 13) + a];               // r*WW + a
        }
    }
    // phase 3: select + aligned float4 stores
    #pragma unroll
    for (int j = 0; j < GITER; ++j) {
        const unsigned c = gtid + (unsigned)j * (unsigned)GSTR;
        if (c < (unsigned)NCHUNKS) {
            float4 v;
            v.x = (mv[j][0] >= 0) ? xv[j][0] : ((mv[j][0] == -1) ? sep : 0.0f);
            v.y = (mv[j][1] >= 0) ? xv[j][1] : ((mv[j][1] == -1) ? sep : 0.0f);
            v.z = (mv[j][2] >= 0) ? xv[j][2] : ((mv[j][2] == -1) ? sep : 0.0f);
            v.w = (mv[j][3] >= 0) ? xv[j][3] : ((mv[j][3] == -1) ? sep : 0.0f);
            ((float4*)out)[c] = v;
        }
    }
}

// ---------------- fallback (no ws): self-contained tiled gather ----------------
#define FTILE   512
#define FHCHUNK 32

__global__ __launch_bounds__(256) void tb_gather_tiled(const float* __restrict__ x,
                                                       const int* __restrict__ xi,
                                                       const int* __restrict__ Nv,
                                                       const float* __restrict__ sep_param,
                                                       float* __restrict__ out) {
    __shared__ int s_s0[N_MAXC], s_e0[N_MAXC], s_sn[N_MAXC], s_en[N_MAXC];
    __shared__ int s_map[FTILE];
    const int b = blockIdx.z, h0 = blockIdx.y * FHCHUNK, t0 = blockIdx.x * FTILE;
    const int tid = threadIdx.x, Nb = Nv[b];
    if (tid < N_MAXC) {
        s_s0[tid] = xi[(b * N_MAXC + tid) * 2 + 0];
        s_e0[tid] = xi[(b * N_MAXC + tid) * 2 + 1];
    }
    __syncthreads();
    if (tid == 0) {
        int c = 0;
        for (int i = 0; i < N_MAXC; ++i) {
            int w = s_e0[i] - s_s0[i]; if (w < 0) w = 0;
            int wvv = (i < Nb) ? w : 0;
            c += wvv;
            s_sn[i] = c - wvv + i;
            s_en[i] = c + i;
        }
    }
    __syncthreads();
    for (int j = tid; j < FTILE; j += 256) {
        int t = t0 + j, m = -2;
        if (t < W_OUTC) {
            int lo = 0, hi = Nb;
            while (lo < hi) { int mid = (lo + hi) >> 1; if (s_en[mid] <= t) lo = mid + 1; else hi = mid; }
            int i = lo, ic = (i < N_MAXC - 1) ? i : (N_MAXC - 1);
            if (i < Nb) {
                int sn = s_sn[ic], en = s_en[ic];
                if (t >= sn && en > sn && s_e0[ic] > s_s0[ic]) {
                    int src = s_s0[ic] + (t - sn);
                    m = src < 0 ? 0 : (src > WW - 1 ? WW - 1 : src);
                }
            }
            if (m == -2 && i >= 1) {
                int ep = s_en[i - 1];
                if (t == ep && (i - 1) < (Nb - 1) && ep < WW) m = -1;
            }
        }
        s_map[j] = m;
    }
    __syncthreads();
    const float sep = sep_param[0];
    const float* xb = x + (size_t)b * HH * WW;
    float* ob = out + (size_t)b * HH * W_OUTC;
    for (int r = 0; r < FHCHUNK; ++r) {
        const int h = h0 + r;
        const float* xr = xb + (size_t)h * WW;
        float* orow = ob + (size_t)h * W_OUTC;
        for (int j = tid; j < FTILE; j += 256) {
            int t = t0 + j;
            if (t < W_OUTC) {
                int m = s_map[j];
                orow[t] = (m >= 0) ? xr[m] : ((m == -1) ? sep : 0.0f);
            }
        }
    }
}

extern "C" void kernel_launch(void* const* d_in, const int* in_sizes, int n_in,
                              void* d_out, int out_size, void* d_ws, size_t ws_size,
                              hipStream_t stream) {
    const float* x   = (const float*)d_in[0];
    const int*   xi  = (const int*)  d_in[1];
    const int*   Nv  = (const int*)  d_in[2];
    const int*   xl  = (const int*)  d_in[3];
    const float* sep = (const float*)d_in[4];
    float*       out = (float*)d_out;

    const bool use_ws = (ws_size >= MAP_BYTES) && (d_ws != nullptr);
    int* map = use_ws ? (int*)d_ws : nullptr;

    tb_meta<<<dim3(BB, 13), dim3(256), 0, stream>>>(xi, Nv, xl, out, map);

    if (use_ws) {
        tb_gather_flat<<<dim3(GBLK), dim3(256), 0, stream>>>(x, map, sep, out);
    } else {
        dim3 grid((W_OUTC + FTILE - 1) / FTILE, HH / FHCHUNK, BB);
        tb_gather_tiled<<<grid, dim3(256), 0, stream>>>(x, xi, Nv, sep, out);
    }
}

// Round 6
// 127.209 us; speedup vs baseline: 1.2027x; 1.0660x over previous
//
#include <hip/hip_runtime.h>

// Problem constants (static per reference setup_inputs)
#define BB     16
#define HH     128
#define WW     8192
#define N_MAXC 128
#define W_OUTC 6271
#define MROW   6272    // padded map row stride (16B-aligned rows)
#define SEP_CLASS 2.0f

// d_out layout (all float32): x_new [B*H*W_OUT] | xi_new [B*N_MAX*2] | xl_new [B*W_OUT]
#define X_ELEMS (BB * HH * W_OUTC)            // 12,843,008
#define XI_OFF  (X_ELEMS)
#define XL_OFF  (X_ELEMS + BB * N_MAXC * 2)

#define BATCH_ELEMS  (HH * W_OUTC)            // 802,688 (divisible by 4)
#define BATCH_CHUNKS (BATCH_ELEMS / 4)        // 200,672
#define RPB   128                             // ranges (blocks) per batch
#define CPB   1568                            // chunks per block: 128*1568 >= 200,672
#define KPT   7                               // chunks per thread: 7*256 = 1792 >= 1568

#define MAP_BYTES ((size_t)(BB * MROW) * sizeof(int))

#define MTILE 512                             // meta cols per block; 13*512 >= 6271

typedef float  vf4 __attribute__((ext_vector_type(4)));   // native vector (nontemporal-ok)
typedef int    vi4 __attribute__((ext_vector_type(4)));

// ---------------- kernel A: map + xi_new + xl_new ----------------
__global__ __launch_bounds__(256) void tb_meta(const int* __restrict__ xi,
                                               const int* __restrict__ Nv,
                                               const int* __restrict__ xl,
                                               float* __restrict__ out,
                                               int* __restrict__ map) {
    __shared__ int s_s0[N_MAXC], s_e0[N_MAXC], s_scan[N_MAXC], s_sn[N_MAXC], s_en[N_MAXC];
    const int b   = blockIdx.x;
    const int tid = threadIdx.x;
    const int Nb  = Nv[b];

    int wv = 0;
    if (tid < N_MAXC) {
        int2 se = ((const int2*)xi)[b * N_MAXC + tid];
        s_s0[tid] = se.x; s_e0[tid] = se.y;
        int w = se.y - se.x; if (w < 0) w = 0;
        wv = (tid < Nb) ? w : 0;
        s_scan[tid] = wv;
    }
    __syncthreads();
    // Hillis-Steele inclusive scan (reference: cumsum of masked widths)
    #pragma unroll
    for (int off = 1; off < N_MAXC; off <<= 1) {
        int v = 0;
        if (tid < N_MAXC && tid >= off) v = s_scan[tid - off];
        __syncthreads();
        if (tid < N_MAXC) s_scan[tid] += v;
        __syncthreads();
    }
    if (tid < N_MAXC) {
        int c = s_scan[tid];
        s_sn[tid] = c - wv + tid;   // sn = csum - w_valid + i
        s_en[tid] = c + tid;        // en = csum + i
    }
    __syncthreads();

    if (blockIdx.y == 0 && tid < N_MAXC) {
        const bool valid = tid < Nb;
        out[XI_OFF + (b * N_MAXC + tid) * 2 + 0] = valid ? (float)s_sn[tid] : 0.0f;
        out[XI_OFF + (b * N_MAXC + tid) * 2 + 1] = valid ? (float)s_en[tid] : 0.0f;
    }

    const int t_lo = blockIdx.y * MTILE;
    const int t_hi = (t_lo + MTILE < W_OUTC) ? t_lo + MTILE : W_OUTC;
    for (int t = t_lo + tid; t < t_hi; t += 256) {
        // i = #{valid j : en[j] <= t}; en strictly increasing on [0,Nb)
        int lo = 0, hi = Nb;
        while (lo < hi) { int mid = (lo + hi) >> 1; if (s_en[mid] <= t) lo = mid + 1; else hi = mid; }
        const int i  = lo;
        const int ic = (i < N_MAXC - 1) ? i : (N_MAXC - 1);
        int m = -2;
        if (i < Nb) {
            int sn = s_sn[ic], en = s_en[ic];
            if (t >= sn && en > sn && s_e0[ic] > s_s0[ic]) {
                int src = s_s0[ic] + (t - sn);
                src = src < 0 ? 0 : (src > WW - 1 ? WW - 1 : src);
                m = src;
            }
        }
        if (m == -2 && i >= 1) {
            int ep = s_en[i - 1];
            if (t == ep && (i - 1) < (Nb - 1) && ep < WW) m = -1;
        }
        if (map) map[b * MROW + t] = m;
        float v = (m >= 0) ? (float)xl[b * WW + m] : ((m == -1) ? SEP_CLASS : 0.0f);
        out[XL_OFF + b * W_OUTC + t] = v;
    }
}

// ---------------- kernel B (primary): LDS-map flat gather ----------------
// Block = (batch b, chunk-range r). Map row staged in LDS via int4 (no deps);
// all addressing from LDS, so x loads are the only global-latency ops and are
// mutually independent. 7 float4 chunks per thread.
__global__ __launch_bounds__(256) void tb_gather_lds(const float* __restrict__ x,
                                                     const int* __restrict__ map,
                                                     const float* __restrict__ sep_param,
                                                     float* __restrict__ out) {
    __shared__ __align__(16) int s_map[MROW];
    const int b   = blockIdx.y;
    const int r   = blockIdx.x;
    const int tid = threadIdx.x;

    // stage padded map row: 1568 int4 = 6272 ints
    const vi4* msrc = (const vi4*)(map + (size_t)b * MROW);
    #pragma unroll
    for (int k = 0; k < 7; ++k) {
        int idx = tid + k * 256;
        if (idx < MROW / 4) ((vi4*)s_map)[idx] = msrc[idx];
    }
    __syncthreads();

    const float sep = sep_param[0];
    const int   c0  = r * CPB;                        // batch-local first chunk
    const float* xb = x   + ((size_t)b << 20);        // b * 128 * 8192
    float*       ob = out + (size_t)b * BATCH_ELEMS;  // 16B-aligned (802,688*4B)

    unsigned hh[KPT], tt[KPT];
    int   mv[KPT][4];
    float xv[KPT][4];
    bool  act[KPT];

    // phase 0+1: addresses from LDS map (no global deps)
    #pragma unroll
    for (int k = 0; k < KPT; ++k) {
        int cl = c0 + tid + k * 256;
        act[k] = (tid + k * 256 < CPB) && (cl < BATCH_CHUNKS);
        if (!act[k]) cl = 0;
        const unsigned e = (unsigned)cl * 4u;
        const unsigned h = e / (unsigned)W_OUTC;      // magic-mul div (constant)
        const unsigned t = e - h * (unsigned)W_OUTC;
        hh[k] = h; tt[k] = t;
        #pragma unroll
        for (int kk = 0; kk < 4; ++kk) {
            unsigned tk = t + (unsigned)kk;
            if (tk >= (unsigned)W_OUTC) tk -= (unsigned)W_OUTC;   // row wrap
            mv[k][kk] = s_map[tk];
        }
    }
    // phase 2: independent clamped x loads
    #pragma unroll
    for (int k = 0; k < KPT; ++k) {
        #pragma unroll
        for (int kk = 0; kk < 4; ++kk) {
            unsigned tk = tt[k] + (unsigned)kk;
            unsigned h  = hh[k] + ((tk >= (unsigned)W_OUTC) ? 1u : 0u);
            const int m = mv[k][kk];
            const unsigned a = (m >= 0) ? (unsigned)m : 0u;
            xv[k][kk] = xb[((size_t)h << 13) + a];
        }
    }
    // phase 3: select + aligned nontemporal float4 stores
    #pragma unroll
    for (int k = 0; k < KPT; ++k) {
        if (act[k]) {
            const int cl = c0 + tid + k * 256;
            vf4 v;
            v.x = (mv[k][0] >= 0) ? xv[k][0] : ((mv[k][0] == -1) ? sep : 0.0f);
            v.y = (mv[k][1] >= 0) ? xv[k][1] : ((mv[k][1] == -1) ? sep : 0.0f);
            v.z = (mv[k][2] >= 0) ? xv[k][2] : ((mv[k][2] == -1) ? sep : 0.0f);
            v.w = (mv[k][3] >= 0) ? xv[k][3] : ((mv[k][3] == -1) ? sep : 0.0f);
            __builtin_nontemporal_store(v, ((vf4*)ob) + cl);
        }
    }
}

// ---------------- fallback (no ws): self-contained tiled gather ----------------
#define FTILE   512
#define FHCHUNK 32

__global__ __launch_bounds__(256) void tb_gather_tiled(const float* __restrict__ x,
                                                       const int* __restrict__ xi,
                                                       const int* __restrict__ Nv,
                                                       const float* __restrict__ sep_param,
                                                       float* __restrict__ out) {
    __shared__ int s_s0[N_MAXC], s_e0[N_MAXC], s_sn[N_MAXC], s_en[N_MAXC];
    __shared__ int s_map[FTILE];
    const int b = blockIdx.z, h0 = blockIdx.y * FHCHUNK, t0 = blockIdx.x * FTILE;
    const int tid = threadIdx.x, Nb = Nv[b];
    if (tid < N_MAXC) {
        s_s0[tid] = xi[(b * N_MAXC + tid) * 2 + 0];
        s_e0[tid] = xi[(b * N_MAXC + tid) * 2 + 1];
    }
    __syncthreads();
    if (tid == 0) {
        int c = 0;
        for (int i = 0; i < N_MAXC; ++i) {
            int w = s_e0[i] - s_s0[i]; if (w < 0) w = 0;
            int wvv = (i < Nb) ? w : 0;
            c += wvv;
            s_sn[i] = c - wvv + i;
            s_en[i] = c + i;
        }
    }
    __syncthreads();
    for (int j = tid; j < FTILE; j += 256) {
        int t = t0 + j, m = -2;
        if (t < W_OUTC) {
            int lo = 0, hi = Nb;
            while (lo < hi) { int mid = (lo + hi) >> 1; if (s_en[mid] <= t) lo = mid + 1; else hi = mid; }
            int i = lo, ic = (i < N_MAXC - 1) ? i : (N_MAXC - 1);
            if (i < Nb) {
                int sn = s_sn[ic], en = s_en[ic];
                if (t >= sn && en > sn && s_e0[ic] > s_s0[ic]) {
                    int src = s_s0[ic] + (t - sn);
                    m = src < 0 ? 0 : (src > WW - 1 ? WW - 1 : src);
                }
            }
            if (m == -2 && i >= 1) {
                int ep = s_en[i - 1];
                if (t == ep && (i - 1) < (Nb - 1) && ep < WW) m = -1;
            }
        }
        s_map[j] = m;
    }
    __syncthreads();
    const float sep = sep_param[0];
    const float* xb = x + (size_t)b * HH * WW;
    float* ob = out + (size_t)b * HH * W_OUTC;
    for (int r = 0; r < FHCHUNK; ++r) {
        const int h = h0 + r;
        const float* xr = xb + (size_t)h * WW;
        float* orow = ob + (size_t)h * W_OUTC;
        for (int j = tid; j < FTILE; j += 256) {
            int t = t0 + j;
            if (t < W_OUTC) {
                int m = s_map[j];
                orow[t] = (m >= 0) ? xr[m] : ((m == -1) ? sep : 0.0f);
            }
        }
    }
}

extern "C" void kernel_launch(void* const* d_in, const int* in_sizes, int n_in,
                              void* d_out, int out_size, void* d_ws, size_t ws_size,
                              hipStream_t stream) {
    const float* x   = (const float*)d_in[0];
    const int*   xi  = (const int*)  d_in[1];
    const int*   Nv  = (const int*)  d_in[2];
    const int*   xl  = (const int*)  d_in[3];
    const float* sep = (const float*)d_in[4];
    float*       out = (float*)d_out;

    const bool use_ws = (ws_size >= MAP_BYTES) && (d_ws != nullptr);
    int* map = use_ws ? (int*)d_ws : nullptr;

    tb_meta<<<dim3(BB, 13), dim3(256), 0, stream>>>(xi, Nv, xl, out, map);

    if (use_ws) {
        tb_gather_lds<<<dim3(RPB, BB), dim3(256), 0, stream>>>(x, map, sep, out);
    } else {
        dim3 grid((W_OUTC + FTILE - 1) / FTILE, HH / FHCHUNK, BB);
        tb_gather_tiled<<<grid, dim3(256), 0, stream>>>(x, xi, Nv, sep, out);
    }
}

// Round 7
// 126.105 us; speedup vs baseline: 1.2133x; 1.0087x over previous
//
#include <hip/hip_runtime.h>

// Problem constants (static per reference setup_inputs)
#define BB     16
#define HH     128
#define WW     8192
#define N_MAXC 128
#define W_OUTC 6271
#define SEP_CLASS 2.0f

// d_out layout (all float32): x_new [B*H*W_OUT] | xi_new [B*N_MAX*2] | xl_new [B*W_OUT]
#define X_ELEMS (BB * HH * W_OUTC)            // 12,843,008
#define XI_OFF  (X_ELEMS)
#define XL_OFF  (X_ELEMS + BB * N_MAXC * 2)

#define TCOLS 512                             // columns per tile (13 tiles)
#define HROWS 16                              // rows per block (8 hgroups)
#define NTILE 13                              // ceil(6271/512)

typedef int vi4 __attribute__((ext_vector_type(4)));

// One fused kernel. Block (tile, hgroup, b):
//  1. scan xi -> sn/en in LDS (all blocks, tiny)
//  2. build 512-entry col map in LDS (1 binary search per col, amortized 16 rows)
//  3. hgroup==0: write xl_new for these cols; (0,0): write xi_new
//  4. gather 512 cols x 16 rows; per thread: 4 map values in registers reused
//     across 8 rows -> inner loop is pure independent x-loads + stores.
__global__ __launch_bounds__(256, 4) void tb_fused(const float* __restrict__ x,
                                                   const int* __restrict__ xi,
                                                   const int* __restrict__ Nv,
                                                   const int* __restrict__ xl,
                                                   const float* __restrict__ sep_param,
                                                   float* __restrict__ out) {
    __shared__ int s_s0[N_MAXC], s_e0[N_MAXC], s_scan[N_MAXC], s_sn[N_MAXC], s_en[N_MAXC];
    __shared__ __align__(16) int s_map[TCOLS];

    const int t0  = blockIdx.x * TCOLS;
    const int h0  = blockIdx.y * HROWS;
    const int b   = blockIdx.z;
    const int tid = threadIdx.x;
    const int Nb  = Nv[b];

    // --- 1. scan (reference: csum of masked widths; sn=c-wv+i, en=c+i) ---
    int wv = 0;
    if (tid < N_MAXC) {
        int2 se = ((const int2*)xi)[b * N_MAXC + tid];
        s_s0[tid] = se.x; s_e0[tid] = se.y;
        int w = se.y - se.x; if (w < 0) w = 0;
        wv = (tid < Nb) ? w : 0;
        s_scan[tid] = wv;
    }
    __syncthreads();
    #pragma unroll
    for (int off = 1; off < N_MAXC; off <<= 1) {
        int v = 0;
        if (tid < N_MAXC && tid >= off) v = s_scan[tid - off];
        __syncthreads();
        if (tid < N_MAXC) s_scan[tid] += v;
        __syncthreads();
    }
    if (tid < N_MAXC) {
        int c = s_scan[tid];
        s_sn[tid] = c - wv + tid;
        s_en[tid] = c + tid;
    }
    __syncthreads();

    // --- 2. per-column map for this tile ---
    #pragma unroll
    for (int q = 0; q < 2; ++q) {
        const int j = tid + q * 256;
        const int t = t0 + j;
        int m = -2;
        if (t < W_OUTC) {
            int lo = 0, hi = Nb;
            while (lo < hi) { int mid = (lo + hi) >> 1; if (s_en[mid] <= t) lo = mid + 1; else hi = mid; }
            const int i  = lo;
            const int ic = (i < N_MAXC - 1) ? i : (N_MAXC - 1);
            if (i < Nb) {
                int sn = s_sn[ic], en = s_en[ic];
                if (t >= sn && en > sn && s_e0[ic] > s_s0[ic]) {
                    int src = s_s0[ic] + (t - sn);
                    m = src < 0 ? 0 : (src > WW - 1 ? WW - 1 : src);
                }
            }
            if (m == -2 && i >= 1) {
                int ep = s_en[i - 1];
                if (t == ep && (i - 1) < (Nb - 1) && ep < WW) m = -1;
            }
        }
        s_map[j] = m;
    }

    // --- 3. small outputs (before barrier: uses only s_* already valid) ---
    if (blockIdx.y == 0 && blockIdx.x == 0 && tid < N_MAXC) {
        const bool valid = tid < Nb;
        out[XI_OFF + (b * N_MAXC + tid) * 2 + 0] = valid ? (float)s_sn[tid] : 0.0f;
        out[XI_OFF + (b * N_MAXC + tid) * 2 + 1] = valid ? (float)s_en[tid] : 0.0f;
    }
    __syncthreads();

    if (blockIdx.y == 0) {
        #pragma unroll
        for (int q = 0; q < 2; ++q) {
            const int j = tid + q * 256;
            const int t = t0 + j;
            if (t < W_OUTC) {
                const int m = s_map[j];
                float v = (m >= 0) ? (float)xl[b * WW + m] : ((m == -1) ? SEP_CLASS : 0.0f);
                out[XL_OFF + b * W_OUTC + t] = v;
            }
        }
    }

    // --- 4. bulk gather: 512 cols x 16 rows ---
    const float sep = sep_param[0];
    const int   c   = tid & 127;          // float4-chunk within tile: cols t0+4c..+3
    const int   rb  = tid >> 7;           // row parity (0/1)
    const vi4   mv  = ((const vi4*)s_map)[c];   // 4 map values, reused for 8 rows
    const int   tA  = t0 + 4 * c;

    const float* xb = x   + ((size_t)b << 20);           // b*128*8192
    float*       ob = out + (size_t)b * (HH * W_OUTC);

    const unsigned a0 = (mv.x >= 0) ? (unsigned)mv.x : 0u;
    const unsigned a1 = (mv.y >= 0) ? (unsigned)mv.y : 0u;
    const unsigned a2 = (mv.z >= 0) ? (unsigned)mv.z : 0u;
    const unsigned a3 = (mv.w >= 0) ? (unsigned)mv.w : 0u;
    const float f0 = (mv.x == -1) ? sep : 0.0f;
    const float f1 = (mv.y == -1) ? sep : 0.0f;
    const float f2 = (mv.z == -1) ? sep : 0.0f;
    const float f3 = (mv.w == -1) ? sep : 0.0f;

    if (tA + 3 < W_OUTC) {                // full chunk (all but tail of last tile)
        #pragma unroll
        for (int rr = 0; rr < HROWS / 2; ++rr) {
            const int h = h0 + rb + rr * 2;
            const float* xr = xb + ((size_t)h << 13);
            float* orow = ob + (size_t)h * W_OUTC + tA;
            const float v0 = (mv.x >= 0) ? xr[a0] : f0;
            const float v1 = (mv.y >= 0) ? xr[a1] : f1;
            const float v2 = (mv.z >= 0) ? xr[a2] : f2;
            const float v3 = (mv.w >= 0) ? xr[a3] : f3;
            orow[0] = v0; orow[1] = v1; orow[2] = v2; orow[3] = v3;
        }
    } else if (tA < W_OUTC) {             // tail chunk: per-element guard
        const int nrem = W_OUTC - tA;     // 1..3
        #pragma unroll
        for (int rr = 0; rr < HROWS / 2; ++rr) {
            const int h = h0 + rb + rr * 2;
            const float* xr = xb + ((size_t)h << 13);
            float* orow = ob + (size_t)h * W_OUTC + tA;
            if (nrem > 0) orow[0] = (mv.x >= 0) ? xr[a0] : f0;
            if (nrem > 1) orow[1] = (mv.y >= 0) ? xr[a1] : f1;
            if (nrem > 2) orow[2] = (mv.z >= 0) ? xr[a2] : f2;
        }
    }
}

extern "C" void kernel_launch(void* const* d_in, const int* in_sizes, int n_in,
                              void* d_out, int out_size, void* d_ws, size_t ws_size,
                              hipStream_t stream) {
    const float* x   = (const float*)d_in[0];
    const int*   xi  = (const int*)  d_in[1];
    const int*   Nv  = (const int*)  d_in[2];
    const int*   xl  = (const int*)  d_in[3];
    const float* sep = (const float*)d_in[4];
    float*       out = (float*)d_out;

    dim3 grid(NTILE, HH / HROWS, BB);     // 13 x 8 x 16 = 1664 blocks
    tb_fused<<<grid, dim3(256), 0, stream>>>(x, xi, Nv, xl, sep, out);
}